// Round 2
// baseline (232.812 us; speedup 1.0000x reference)
//
#include <hip/hip_runtime.h>
#include <hip/hip_bf16.h>

// Problem constants (from reference)
#define NN 50000      // nodes
#define NE 800000     // edges
#define NR 16         // relations == IN_DIM
#define HD 128        // hidden/out dim
#define LIND 512      // MLP hidden

// Frontier capacities (expected sizes ~16 / ~256 / ~16 edges / ~256 edges;
// Poisson margins are astronomically safe; overflow is clamped, never OOB)
#define CAP1 1024     // |S1| nodes needed at layer-1 output
#define CAP0 4096     // |S0| nodes needed at layer-0 output
#define E0CAP 4096    // edges with dst==0
#define E1CAP 32768   // edges with dst in S1

// counter slots
#define C_N1 0
#define C_N0 1
#define C_E0 2
#define C_E1 3

// ---------------- init: zero counters+maps+agg buffers, build M0 ----------------
// M0[c][o] = W0[c][c][o]  (layer-0 input is onehot(cls))
__global__ void k_init(int* zero_ints, float* agg0, float* agg1, float* m0,
                       const float* __restrict__ W0) {
    int tid = blockIdx.x * blockDim.x + threadIdx.x;
    int stride = gridDim.x * blockDim.x;
    for (int j = tid; j < 8 + 2 * NN; j += stride) zero_ints[j] = 0;
    for (int j = tid; j < CAP0 * HD; j += stride) agg0[j] = 0.f;
    for (int j = tid; j < CAP1 * HD; j += stride) agg1[j] = 0.f;
    for (int j = tid; j < NR * HD; j += stride) {
        int c = j >> 7, o = j & 127;
        m0[j] = W0[c * ((NR + 1) * HD) + o];   // (c*NR + c)*HD + o
    }
}

// ---------------- scan A: edges with dst==0 -> e0 list + S1 set ----------------
__global__ void k_scanA(const int* __restrict__ src, const int* __restrict__ dst,
                        int* map1, int* list1, int* e0_src, int* cnt) {
    int tid = blockIdx.x * blockDim.x + threadIdx.x;
    int stride = gridDim.x * blockDim.x;
    for (int e = tid; e < NE; e += stride) {
        if (dst[e] == 0) {
            int s = src[e];
            int i = atomicAdd(&cnt[C_E0], 1);
            if (i < E0CAP) e0_src[i] = s;
            if (atomicCAS(&map1[s], 0, -1) == 0) {
                int slot = atomicAdd(&cnt[C_N1], 1);
                if (slot < CAP1) { list1[slot] = s; map1[s] = slot + 2; }
                else map1[s] = 1;   // overflow marker (unreachable in practice)
            }
        }
    }
}

// ---------------- scan B1: edges with dst in S1 -> E1 list + S0 set ----------------
__global__ void k_scanB1(const int* __restrict__ src, const int* __restrict__ dst,
                         const int* __restrict__ map1, int* map0, int* list0,
                         int* e1_src, int* e1_dslot, int* cnt) {
    int tid = blockIdx.x * blockDim.x + threadIdx.x;
    int stride = gridDim.x * blockDim.x;
    for (int e = tid; e < NE; e += stride) {
        int m = map1[dst[e]];
        if (m >= 2) {
            int s = src[e];
            int i = atomicAdd(&cnt[C_E1], 1);
            if (i < E1CAP) { e1_src[i] = s; e1_dslot[i] = m - 2; }
            if (atomicCAS(&map0[s], 0, -1) == 0) {
                int slot = atomicAdd(&cnt[C_N0], 1);
                if (slot < CAP0) { list0[slot] = s; map0[s] = slot + 2; }
                else map0[s] = 1;
            }
        }
    }
}

// ---------------- scan B2: edges with dst in S0 -> accumulate agg0 ----------------
// layer-0 message for src node s is M0[cls[s]] * norm[s]
__global__ void k_scanB2(const int* __restrict__ src, const int* __restrict__ dst,
                         const int* __restrict__ map0, const int* __restrict__ cls,
                         const float* __restrict__ norm, const float* __restrict__ m0,
                         float* agg0) {
    int tid = blockIdx.x * blockDim.x + threadIdx.x;
    int stride = gridDim.x * blockDim.x;
    for (int e = tid; e < NE; e += stride) {
        int m = map0[dst[e]];
        if (m >= 2) {
            int s = src[e];
            float nm = norm[s];
            const float* row = m0 + (cls[s] << 7);
            float* drow = agg0 + ((size_t)(m - 2) << 7);
            #pragma unroll 4
            for (int j = 0; j < HD; j++) atomicAdd(&drow[j], row[j] * nm);
        }
    }
}

// ---------------- per-node message: msg = (relu(agg) @ W[cls]) * norm ----------------
// one block (128 threads) per compact node slot; LDS-broadcast h, coalesced W cols
__global__ void k_msg(const int* __restrict__ cnt, int cidx, int cap,
                      const int* __restrict__ list, const int* __restrict__ cls,
                      const float* __restrict__ norm, const float* __restrict__ agg,
                      const float* __restrict__ W, float* msg) {
    int b = blockIdx.x;
    int n = cnt[cidx]; if (n > cap) n = cap;
    if (b >= n) return;
    __shared__ float sh[HD];
    int t = threadIdx.x;
    sh[t] = fmaxf(agg[(b << 7) + t], 0.f);
    __syncthreads();
    int node = list[b];
    int c = cls[node];
    float nm = norm[node];
    const float* w = W + c * (HD * HD) + t;
    float acc = 0.f;
    #pragma unroll 8
    for (int i = 0; i < HD; i++) acc = fmaf(sh[i], w[i << 7], acc);
    msg[(b << 7) + t] = acc * nm;
}

// ---------------- aggregate E1: agg1[dslot] += msg1[slot0(src)] ----------------
__global__ void k_agg1(const int* __restrict__ cnt, const int* __restrict__ e1_src,
                       const int* __restrict__ e1_dslot, const int* __restrict__ map0,
                       const float* __restrict__ msg1, float* agg1) {
    int e1n = cnt[C_E1]; if (e1n > E1CAP) e1n = E1CAP;
    int total = e1n << 7;
    int tid = blockIdx.x * blockDim.x + threadIdx.x;
    int stride = gridDim.x * blockDim.x;
    for (int idx = tid; idx < total; idx += stride) {
        int ei = idx >> 7, j = idx & 127;
        int dslot = e1_dslot[ei];
        int sslot = map0[e1_src[ei]] - 2;
        if (sslot >= 0 && sslot < CAP0 && dslot >= 0 && dslot < CAP1)
            atomicAdd(&agg1[(dslot << 7) + j], msg1[(sslot << 7) + j]);
    }
}

// ---------------- head: agg2[0] -> softmax -> actor/critic MLPs ----------------
__global__ void __launch_bounds__(512)
k_head(const int* __restrict__ cnt, const int* __restrict__ e0_src,
       const int* __restrict__ map1, const float* __restrict__ msg2,
       const float* __restrict__ a1w, const float* __restrict__ a1b,
       const float* __restrict__ a2w, const float* __restrict__ a2b,
       const float* __restrict__ c1w, const float* __restrict__ c1b,
       const float* __restrict__ c2w, const float* __restrict__ c2b,
       float* out) {
    __shared__ float sh_a[HD];     // agg2 row, then root (softmax)
    __shared__ float sh_b[HD];     // exp values
    __shared__ float sh_z[LIND];   // actor hidden
    __shared__ float sh_zc[LIND];  // critic hidden
    __shared__ float sh_p[LIND];   // partials
    int t = threadIdx.x;

    int e0n = cnt[C_E0]; if (e0n > E0CAP) e0n = E0CAP;
    if (t < HD) {
        float acc = 0.f;
        for (int i = 0; i < e0n; i++) {
            int slot = map1[e0_src[i]] - 2;
            if (slot >= 0 && slot < CAP1) acc += msg2[(slot << 7) + t];
        }
        sh_a[t] = acc;
    }
    __syncthreads();
    // softmax over 128 (all threads compute redundantly from LDS broadcasts)
    float mx = -3.0e38f;
    for (int i = 0; i < HD; i++) mx = fmaxf(mx, sh_a[i]);
    float ex = 0.f;
    if (t < HD) ex = expf(sh_a[t] - mx);
    __syncthreads();
    if (t < HD) sh_b[t] = ex;
    __syncthreads();
    float sum = 0.f;
    for (int i = 0; i < HD; i++) sum += sh_b[i];
    if (t < HD) sh_a[t] = ex / sum;    // sh_a := root
    __syncthreads();

    // hidden layers (512 threads, one output each, both MLPs)
    {
        float z = a1b[t];
        float zc = c1b[t];
        for (int i = 0; i < HD; i++) {
            float r = sh_a[i];
            z  = fmaf(r, a1w[i * LIND + t], z);
            zc = fmaf(r, c1w[i * LIND + t], zc);
        }
        sh_z[t]  = fmaxf(z, 0.f);
        sh_zc[t] = fmaxf(zc, 0.f);
    }
    __syncthreads();

    // probs: split K=512 across 4 groups of 128 threads
    {
        int o = t & 127, g = t >> 7;
        float p = 0.f;
        int k0 = g << 7;
        for (int k = k0; k < k0 + 128; k++) p = fmaf(sh_z[k], a2w[k * HD + o], p);
        sh_p[t] = p;
    }
    __syncthreads();
    if (t < HD) out[t] = a2b[t] + sh_p[t] + sh_p[t + 128] + sh_p[t + 256] + sh_p[t + 384];

    // value
    float v = sh_zc[t] * c2w[t];
    __syncthreads();
    sh_p[t] = v;
    __syncthreads();
    if (t == 0) {
        float vv = c2b[0];
        for (int k = 0; k < LIND; k++) vv += sh_p[k];
        out[HD] = vv;
    }
}

extern "C" void kernel_launch(void* const* d_in, const int* in_sizes, int n_in,
                              void* d_out, int out_size, void* d_ws, size_t ws_size,
                              hipStream_t stream) {
    const int*   cls  = (const int*)d_in[0];
    const float* norm = (const float*)d_in[1];
    const int*   src  = (const int*)d_in[2];
    const int*   dst  = (const int*)d_in[3];
    const float* W0   = (const float*)d_in[4];
    const float* W1   = (const float*)d_in[5];
    const float* W2   = (const float*)d_in[6];
    const float* a1w  = (const float*)d_in[7];
    const float* a1b  = (const float*)d_in[8];
    const float* a2w  = (const float*)d_in[9];
    const float* a2b  = (const float*)d_in[10];
    const float* c1w  = (const float*)d_in[11];
    const float* c1b  = (const float*)d_in[12];
    const float* c2w  = (const float*)d_in[13];
    const float* c2b  = (const float*)d_in[14];
    float* out = (float*)d_out;

    // workspace layout (bytes, 16-aligned); total ~5.95 MB
    char* ws = (char*)d_ws;
    int*   cnt      = (int*)(ws + 0);        // 8 ints
    int*   map1     = (int*)(ws + 32);       // NN ints
    int*   map0     = (int*)(ws + 200032);   // NN ints
    int*   list1    = (int*)(ws + 400032);   // CAP1 ints
    int*   list0    = (int*)(ws + 404128);   // CAP0 ints
    int*   e0_src   = (int*)(ws + 420512);   // E0CAP ints
    int*   e1_src   = (int*)(ws + 436896);   // E1CAP ints
    int*   e1_dslot = (int*)(ws + 567968);   // E1CAP ints
    float* M0       = (float*)(ws + 699040); // NR*HD
    float* agg0     = (float*)(ws + 707232); // CAP0*HD
    float* msg1     = (float*)(ws + 2804384);// CAP0*HD
    float* agg1     = (float*)(ws + 4901536);// CAP1*HD
    float* msg2     = (float*)(ws + 5425824);// CAP1*HD

    k_init<<<512, 256, 0, stream>>>(cnt, agg0, agg1, M0, W0);
    k_scanA<<<1600, 256, 0, stream>>>(src, dst, map1, list1, e0_src, cnt);
    k_scanB1<<<1600, 256, 0, stream>>>(src, dst, map1, map0, list0, e1_src, e1_dslot, cnt);
    k_scanB2<<<1600, 256, 0, stream>>>(src, dst, map0, cls, norm, M0, agg0);
    k_msg<<<CAP0, 128, 0, stream>>>(cnt, C_N0, CAP0, list0, cls, norm, agg0, W1, msg1);
    k_agg1<<<128, 256, 0, stream>>>(cnt, e1_src, e1_dslot, map0, msg1, agg1);
    k_msg<<<CAP1, 128, 0, stream>>>(cnt, C_N1, CAP1, list1, cls, norm, agg1, W2, msg2);
    k_head<<<1, 512, 0, stream>>>(cnt, e0_src, map1, msg2,
                                  a1w, a1b, a2w, a2b, c1w, c1b, c2w, c2b, out);
}

// Round 3
// 192.186 us; speedup vs baseline: 1.2114x; 1.2114x over previous
//
#include <hip/hip_runtime.h>
#include <hip/hip_bf16.h>

// Problem constants (from reference)
#define NN 50000      // nodes
#define NE 800000     // edges
#define NR 16         // relations == IN_DIM
#define HD 128        // hidden/out dim
#define LIND 512      // MLP hidden

// Frontier capacities (expected ~16 / ~256 nodes, ~16 / ~256 edges)
#define CAP1 1024
#define CAP0 4096
#define E0CAP 4096
#define E1CAP 32768

// counter slots
#define C_N1 0
#define C_N0 1
#define C_E0 2
#define C_E1 3

// ---------------- init: zero counters+maps+agg buffers+out, build M0 ----------------
__global__ void k_init(int* zero_ints, float* agg0, float* agg1, float* m0,
                       const float* __restrict__ W0, float* out) {
    int tid = blockIdx.x * blockDim.x + threadIdx.x;
    int stride = gridDim.x * blockDim.x;
    for (int j = tid; j < 8 + 2 * NN; j += stride) zero_ints[j] = 0;
    for (int j = tid; j < CAP0 * HD; j += stride) agg0[j] = 0.f;
    for (int j = tid; j < CAP1 * HD; j += stride) agg1[j] = 0.f;
    for (int j = tid; j < NR * HD; j += stride) {
        int c = j >> 7, o = j & 127;
        m0[j] = W0[c * ((NR + 1) * HD) + o];   // (c*NR + c)*HD + o
    }
    for (int j = tid; j < HD + 1; j += stride) out[j] = 0.f;
}

// ---------------- scan A: edges with dst==0 -> e0 list + S1 set ----------------
__global__ void k_scanA(const int* __restrict__ src, const int* __restrict__ dst,
                        int* map1, int* list1, int* e0_src, int* cnt) {
    int tid = blockIdx.x * blockDim.x + threadIdx.x;
    int stride = gridDim.x * blockDim.x;
    for (int e = tid; e < NE; e += stride) {
        if (dst[e] == 0) {
            int s = src[e];
            int i = atomicAdd(&cnt[C_E0], 1);
            if (i < E0CAP) e0_src[i] = s;
            if (atomicCAS(&map1[s], 0, -1) == 0) {
                int slot = atomicAdd(&cnt[C_N1], 1);
                if (slot < CAP1) { list1[slot] = s; map1[s] = slot + 2; }
                else map1[s] = 1;
            }
        }
    }
}

// ---------------- scan B1: edges with dst in S1 -> E1 list + S0 set ----------------
__global__ void k_scanB1(const int* __restrict__ src, const int* __restrict__ dst,
                         const int* __restrict__ map1, int* map0, int* list0,
                         int* e1_src, int* e1_dslot, int* cnt) {
    int tid = blockIdx.x * blockDim.x + threadIdx.x;
    int stride = gridDim.x * blockDim.x;
    for (int e = tid; e < NE; e += stride) {
        int m = map1[dst[e]];
        if (m >= 2) {
            int s = src[e];
            int i = atomicAdd(&cnt[C_E1], 1);
            if (i < E1CAP) { e1_src[i] = s; e1_dslot[i] = m - 2; }
            if (atomicCAS(&map0[s], 0, -1) == 0) {
                int slot = atomicAdd(&cnt[C_N0], 1);
                if (slot < CAP0) { list0[slot] = s; map0[s] = slot + 2; }
                else map0[s] = 1;
            }
        }
    }
}

// ---------------- scan B2: edges with dst in S0 -> accumulate agg0 ----------------
__global__ void k_scanB2(const int* __restrict__ src, const int* __restrict__ dst,
                         const int* __restrict__ map0, const int* __restrict__ cls,
                         const float* __restrict__ norm, const float* __restrict__ m0,
                         float* agg0) {
    int tid = blockIdx.x * blockDim.x + threadIdx.x;
    int stride = gridDim.x * blockDim.x;
    for (int e = tid; e < NE; e += stride) {
        int m = map0[dst[e]];
        if (m >= 2) {
            int s = src[e];
            float nm = norm[s];
            const float* row = m0 + (cls[s] << 7);
            float* drow = agg0 + ((size_t)(m - 2) << 7);
            #pragma unroll 4
            for (int j = 0; j < HD; j++) atomicAdd(&drow[j], row[j] * nm);
        }
    }
}

// ---------------- per-node message: msg = (relu(agg) @ W[cls]) * norm ----------------
__global__ void k_msg(const int* __restrict__ cnt, int cidx, int cap,
                      const int* __restrict__ list, const int* __restrict__ cls,
                      const float* __restrict__ norm, const float* __restrict__ agg,
                      const float* __restrict__ W, float* msg) {
    int b = blockIdx.x;
    int n = cnt[cidx]; if (n > cap) n = cap;
    if (b >= n) return;
    __shared__ float sh[HD];
    int t = threadIdx.x;
    sh[t] = fmaxf(agg[(b << 7) + t], 0.f);
    __syncthreads();
    int node = list[b];
    int c = cls[node];
    float nm = norm[node];
    const float* w = W + c * (HD * HD) + t;
    float acc = 0.f;
    #pragma unroll 8
    for (int i = 0; i < HD; i++) acc = fmaf(sh[i], w[i << 7], acc);
    msg[(b << 7) + t] = acc * nm;
}

// ---------------- aggregate E1: agg1[dslot] += msg1[slot0(src)] ----------------
__global__ void k_agg1(const int* __restrict__ cnt, const int* __restrict__ e1_src,
                       const int* __restrict__ e1_dslot, const int* __restrict__ map0,
                       const float* __restrict__ msg1, float* agg1) {
    int e1n = cnt[C_E1]; if (e1n > E1CAP) e1n = E1CAP;
    int total = e1n << 7;
    int tid = blockIdx.x * blockDim.x + threadIdx.x;
    int stride = gridDim.x * blockDim.x;
    for (int idx = tid; idx < total; idx += stride) {
        int ei = idx >> 7, j = idx & 127;
        int dslot = e1_dslot[ei];
        int sslot = map0[e1_src[ei]] - 2;
        if (sslot >= 0 && sslot < CAP0 && dslot >= 0 && dslot < CAP1)
            atomicAdd(&agg1[(dslot << 7) + j], msg1[(sslot << 7) + j]);
    }
}

// ---------------- hidden: 16 blocks; each recomputes root, does a 16-row k-slice ----
// blocks 0..7: actor (a1w), blocks 8..15: critic (c1w). partX[g][t] in ws.
__global__ void __launch_bounds__(512)
k_hidden(const int* __restrict__ cnt, const int* __restrict__ e0_src,
         const int* __restrict__ map1, const float* __restrict__ msg2,
         const float* __restrict__ a1w, const float* __restrict__ c1w,
         float* partA, float* partC) {
    __shared__ float sh_a[HD];
    __shared__ float sh_r[HD];
    int t = threadIdx.x;
    int b = blockIdx.x;

    // root = softmax(agg2[0]) — recomputed per block (tiny, L2-hot)
    int e0n = cnt[C_E0]; if (e0n > E0CAP) e0n = E0CAP;
    if (t < HD) {
        float acc = 0.f;
        for (int i = 0; i < e0n; i++) {
            int slot = map1[e0_src[i]] - 2;
            if (slot >= 0 && slot < CAP1) acc += msg2[(slot << 7) + t];
        }
        sh_a[t] = acc;
    }
    __syncthreads();
    float mx = -3.0e38f;
    for (int i = 0; i < HD; i++) mx = fmaxf(mx, sh_a[i]);
    float ex = (t < HD) ? expf(sh_a[t] - mx) : 0.f;
    __syncthreads();
    if (t < HD) sh_a[t] = ex;
    __syncthreads();
    float sum = 0.f;
    for (int i = 0; i < HD; i++) sum += sh_a[i];
    if (t < HD) sh_r[t] = ex / sum;
    __syncthreads();

    int m = b >> 3;          // 0 = actor, 1 = critic
    int g = b & 7;
    int i0 = g << 4;         // 16 rows per block
    const float* W = m ? c1w : a1w;
    float p = 0.f;
    #pragma unroll
    for (int i = i0; i < i0 + 16; i++) p = fmaf(sh_r[i], W[i * LIND + t], p);
    (m ? partC : partA)[(g << 9) + t] = p;
}

// ---------------- out: blocks 0..7 probs k-slices (atomicAdd), block 8 value ------
__global__ void __launch_bounds__(128)
k_out(const float* __restrict__ partA, const float* __restrict__ partC,
      const float* __restrict__ a1b, const float* __restrict__ a2w,
      const float* __restrict__ a2b, const float* __restrict__ c1b,
      const float* __restrict__ c2w, const float* __restrict__ c2b,
      float* out) {
    int t = threadIdx.x;
    int b = blockIdx.x;
    if (b < 8) {
        __shared__ float z[64];
        int k0 = b << 6;
        if (t < 64) {
            int k = k0 + t;
            float s = a1b[k];
            #pragma unroll
            for (int g = 0; g < 8; g++) s += partA[(g << 9) + k];
            z[t] = fmaxf(s, 0.f);
        }
        __syncthreads();
        float acc = 0.f;
        #pragma unroll 8
        for (int j = 0; j < 64; j++) acc = fmaf(z[j], a2w[(k0 + j) * HD + t], acc);
        if (b == 0) acc += a2b[t];
        atomicAdd(&out[t], acc);
    } else {
        __shared__ float red[128];
        float acc = 0.f;
        for (int k = t; k < LIND; k += 128) {
            float s = c1b[k];
            #pragma unroll
            for (int g = 0; g < 8; g++) s += partC[(g << 9) + k];
            acc = fmaf(fmaxf(s, 0.f), c2w[k], acc);
        }
        red[t] = acc;
        __syncthreads();
        if (t == 0) {
            float vv = c2b[0];
            for (int k = 0; k < 128; k++) vv += red[k];
            out[HD] = vv;
        }
    }
}

extern "C" void kernel_launch(void* const* d_in, const int* in_sizes, int n_in,
                              void* d_out, int out_size, void* d_ws, size_t ws_size,
                              hipStream_t stream) {
    const int*   cls  = (const int*)d_in[0];
    const float* norm = (const float*)d_in[1];
    const int*   src  = (const int*)d_in[2];
    const int*   dst  = (const int*)d_in[3];
    const float* W0   = (const float*)d_in[4];
    const float* W1   = (const float*)d_in[5];
    const float* W2   = (const float*)d_in[6];
    const float* a1w  = (const float*)d_in[7];
    const float* a1b  = (const float*)d_in[8];
    const float* a2w  = (const float*)d_in[9];
    const float* a2b  = (const float*)d_in[10];
    const float* c1w  = (const float*)d_in[11];
    const float* c1b  = (const float*)d_in[12];
    const float* c2w  = (const float*)d_in[13];
    const float* c2b  = (const float*)d_in[14];
    float* out = (float*)d_out;

    // workspace layout (bytes); total ~5.95 MB
    char* ws = (char*)d_ws;
    int*   cnt      = (int*)(ws + 0);
    int*   map1     = (int*)(ws + 32);
    int*   map0     = (int*)(ws + 200032);
    int*   list1    = (int*)(ws + 400032);
    int*   list0    = (int*)(ws + 404128);
    int*   e0_src   = (int*)(ws + 420512);
    int*   e1_src   = (int*)(ws + 436896);
    int*   e1_dslot = (int*)(ws + 567968);
    float* M0       = (float*)(ws + 699040);
    float* agg0     = (float*)(ws + 707232);   // CAP0*HD — dead after k_msg(W1)
    float* msg1     = (float*)(ws + 2804384);
    float* agg1     = (float*)(ws + 4901536);
    float* msg2     = (float*)(ws + 5425824);
    // overlay MLP partials onto the dead agg0 region (k_hidden runs after k_msg(W1))
    float* partA    = (float*)(ws + 707232);           // 8*512 f32
    float* partC    = (float*)(ws + 707232 + 16384);   // 8*512 f32

    k_init<<<512, 256, 0, stream>>>(cnt, agg0, agg1, M0, W0, out);
    k_scanA<<<1600, 256, 0, stream>>>(src, dst, map1, list1, e0_src, cnt);
    k_scanB1<<<1600, 256, 0, stream>>>(src, dst, map1, map0, list0, e1_src, e1_dslot, cnt);
    k_scanB2<<<1600, 256, 0, stream>>>(src, dst, map0, cls, norm, M0, agg0);
    k_msg<<<CAP0, 128, 0, stream>>>(cnt, C_N0, CAP0, list0, cls, norm, agg0, W1, msg1);
    k_agg1<<<128, 256, 0, stream>>>(cnt, e1_src, e1_dslot, map0, msg1, agg1);
    k_msg<<<CAP1, 128, 0, stream>>>(cnt, C_N1, CAP1, list1, cls, norm, agg1, W2, msg2);
    k_hidden<<<16, 512, 0, stream>>>(cnt, e0_src, map1, msg2, a1w, c1w, partA, partC);
    k_out<<<9, 128, 0, stream>>>(partA, partC, a1b, a2w, a2b, c1b, c2w, c2b, out);
}

// Round 4
// 150.529 us; speedup vs baseline: 1.5466x; 1.2767x over previous
//
#include <hip/hip_runtime.h>
#include <hip/hip_bf16.h>

// Problem constants (from reference)
#define NN 50000      // nodes
#define NE 800000     // edges
#define NR 16         // relations == IN_DIM
#define HD 128        // hidden/out dim
#define LIND 512      // MLP hidden

// Frontier capacities (expected ~16 / ~256 nodes, ~16 / ~256 edges)
#define CAP1 1024
#define CAP0 4096
#define E0CAP 4096
#define E1CAP 32768

// counter slots
#define C_N1 0
#define C_N0 1
#define C_E0 2
#define C_E1 3

// ---------------- init: zero counters+maps+w0sum+agg1+out, build M0 ----------------
__global__ void k_init(int* zero_ints, float* w0sum, float* agg1, float* m0,
                       const float* __restrict__ W0, float* out) {
    int tid = blockIdx.x * blockDim.x + threadIdx.x;
    int stride = gridDim.x * blockDim.x;
    for (int j = tid; j < 8 + 2 * NN; j += stride) zero_ints[j] = 0;
    for (int j = tid; j < CAP0 * NR; j += stride) w0sum[j] = 0.f;
    for (int j = tid; j < CAP1 * HD; j += stride) agg1[j] = 0.f;
    for (int j = tid; j < NR * HD; j += stride) {
        int c = j >> 7, o = j & 127;
        m0[j] = W0[c * ((NR + 1) * HD) + o];   // (c*NR + c)*HD + o
    }
    for (int j = tid; j < HD + 1; j += stride) out[j] = 0.f;
}

// ---------------- scan A: edges with dst==0 -> e0 list + S1 set ----------------
__global__ void k_scanA(const int* __restrict__ src, const int* __restrict__ dst,
                        int* map1, int* list1, int* e0_src, int* cnt) {
    int tid = blockIdx.x * blockDim.x + threadIdx.x;
    int stride = gridDim.x * blockDim.x;
    for (int e = tid; e < NE; e += stride) {
        if (dst[e] == 0) {
            int s = src[e];
            int i = atomicAdd(&cnt[C_E0], 1);
            if (i < E0CAP) e0_src[i] = s;
            if (atomicCAS(&map1[s], 0, -1) == 0) {
                int slot = atomicAdd(&cnt[C_N1], 1);
                if (slot < CAP1) { list1[slot] = s; map1[s] = slot + 2; }
                else map1[s] = 1;
            }
        }
    }
}

// ---------------- scan B1: edges with dst in S1 -> E1 list + S0 set ----------------
__global__ void k_scanB1(const int* __restrict__ src, const int* __restrict__ dst,
                         const int* __restrict__ map1, int* map0, int* list0,
                         int* e1_src, int* e1_dslot, int* cnt) {
    int tid = blockIdx.x * blockDim.x + threadIdx.x;
    int stride = gridDim.x * blockDim.x;
    for (int e = tid; e < NE; e += stride) {
        int m = map1[dst[e]];
        if (m >= 2) {
            int s = src[e];
            int i = atomicAdd(&cnt[C_E1], 1);
            if (i < E1CAP) { e1_src[i] = s; e1_dslot[i] = m - 2; }
            if (atomicCAS(&map0[s], 0, -1) == 0) {
                int slot = atomicAdd(&cnt[C_N0], 1);
                if (slot < CAP0) { list0[slot] = s; map0[s] = slot + 2; }
                else map0[s] = 1;
            }
        }
    }
}

// ---------------- scan B2: edges with dst in S0 -> w0sum[dslot][cls] += norm ------
// layer-0 message is rank-1 per relation: msg(s) = norm[s] * M0[cls[s]], so
// aggregate ONE scalar per edge instead of 128 atomics per edge.
__global__ void k_scanB2(const int* __restrict__ src, const int* __restrict__ dst,
                         const int* __restrict__ map0, const int* __restrict__ cls,
                         const float* __restrict__ norm, float* w0sum) {
    int tid = blockIdx.x * blockDim.x + threadIdx.x;
    int stride = gridDim.x * blockDim.x;
    for (int e = tid; e < NE; e += stride) {
        int m = map0[dst[e]];
        if (m >= 2) {
            int s = src[e];
            atomicAdd(&w0sum[((m - 2) << 4) + cls[s]], norm[s]);
        }
    }
}

// ---------------- layer-1 message: expand agg0 from w0sum, relu, matvec W1 --------
__global__ void k_msg1(const int* __restrict__ cnt, const int* __restrict__ list,
                       const int* __restrict__ cls, const float* __restrict__ norm,
                       const float* __restrict__ w0sum, const float* __restrict__ m0,
                       const float* __restrict__ W, float* msg) {
    int b = blockIdx.x;
    int n = cnt[C_N0]; if (n > CAP0) n = CAP0;
    if (b >= n) return;
    __shared__ float sh[HD];
    __shared__ float w0[NR];
    int t = threadIdx.x;
    if (t < NR) w0[t] = w0sum[(b << 4) + t];
    __syncthreads();
    float a = 0.f;
    #pragma unroll
    for (int c = 0; c < NR; c++) a = fmaf(w0[c], m0[(c << 7) + t], a);
    sh[t] = fmaxf(a, 0.f);
    __syncthreads();
    int node = list[b];
    int c = cls[node];
    float nm = norm[node];
    const float* w = W + c * (HD * HD) + t;
    float acc = 0.f;
    #pragma unroll 8
    for (int i = 0; i < HD; i++) acc = fmaf(sh[i], w[i << 7], acc);
    msg[(b << 7) + t] = acc * nm;
}

// ---------------- per-node message (layer 2): msg = (relu(agg) @ W[cls]) * norm ---
__global__ void k_msg(const int* __restrict__ cnt, int cidx, int cap,
                      const int* __restrict__ list, const int* __restrict__ cls,
                      const float* __restrict__ norm, const float* __restrict__ agg,
                      const float* __restrict__ W, float* msg) {
    int b = blockIdx.x;
    int n = cnt[cidx]; if (n > cap) n = cap;
    if (b >= n) return;
    __shared__ float sh[HD];
    int t = threadIdx.x;
    sh[t] = fmaxf(agg[(b << 7) + t], 0.f);
    __syncthreads();
    int node = list[b];
    int c = cls[node];
    float nm = norm[node];
    const float* w = W + c * (HD * HD) + t;
    float acc = 0.f;
    #pragma unroll 8
    for (int i = 0; i < HD; i++) acc = fmaf(sh[i], w[i << 7], acc);
    msg[(b << 7) + t] = acc * nm;
}

// ---------------- aggregate E1: agg1[dslot] += msg1[slot0(src)] ----------------
__global__ void k_agg1(const int* __restrict__ cnt, const int* __restrict__ e1_src,
                       const int* __restrict__ e1_dslot, const int* __restrict__ map0,
                       const float* __restrict__ msg1, float* agg1) {
    int e1n = cnt[C_E1]; if (e1n > E1CAP) e1n = E1CAP;
    int total = e1n << 7;
    int tid = blockIdx.x * blockDim.x + threadIdx.x;
    int stride = gridDim.x * blockDim.x;
    for (int idx = tid; idx < total; idx += stride) {
        int ei = idx >> 7, j = idx & 127;
        int dslot = e1_dslot[ei];
        int sslot = map0[e1_src[ei]] - 2;
        if (sslot >= 0 && sslot < CAP0 && dslot >= 0 && dslot < CAP1)
            atomicAdd(&agg1[(dslot << 7) + j], msg1[(sslot << 7) + j]);
    }
}

// ---------------- hidden: 16 blocks; each recomputes root, does a 16-row k-slice ----
__global__ void __launch_bounds__(512)
k_hidden(const int* __restrict__ cnt, const int* __restrict__ e0_src,
         const int* __restrict__ map1, const float* __restrict__ msg2,
         const float* __restrict__ a1w, const float* __restrict__ c1w,
         float* partA, float* partC) {
    __shared__ float sh_a[HD];
    __shared__ float sh_r[HD];
    int t = threadIdx.x;
    int b = blockIdx.x;

    int e0n = cnt[C_E0]; if (e0n > E0CAP) e0n = E0CAP;
    if (t < HD) {
        float acc = 0.f;
        for (int i = 0; i < e0n; i++) {
            int slot = map1[e0_src[i]] - 2;
            if (slot >= 0 && slot < CAP1) acc += msg2[(slot << 7) + t];
        }
        sh_a[t] = acc;
    }
    __syncthreads();
    float mx = -3.0e38f;
    for (int i = 0; i < HD; i++) mx = fmaxf(mx, sh_a[i]);
    float ex = (t < HD) ? expf(sh_a[t] - mx) : 0.f;
    __syncthreads();
    if (t < HD) sh_a[t] = ex;
    __syncthreads();
    float sum = 0.f;
    for (int i = 0; i < HD; i++) sum += sh_a[i];
    if (t < HD) sh_r[t] = ex / sum;
    __syncthreads();

    int m = b >> 3;          // 0 = actor, 1 = critic
    int g = b & 7;
    int i0 = g << 4;         // 16 rows per block
    const float* W = m ? c1w : a1w;
    float p = 0.f;
    #pragma unroll
    for (int i = i0; i < i0 + 16; i++) p = fmaf(sh_r[i], W[i * LIND + t], p);
    (m ? partC : partA)[(g << 9) + t] = p;
}

// ---------------- out: blocks 0..7 probs k-slices (atomicAdd), block 8 value ------
__global__ void __launch_bounds__(128)
k_out(const float* __restrict__ partA, const float* __restrict__ partC,
      const float* __restrict__ a1b, const float* __restrict__ a2w,
      const float* __restrict__ a2b, const float* __restrict__ c1b,
      const float* __restrict__ c2w, const float* __restrict__ c2b,
      float* out) {
    int t = threadIdx.x;
    int b = blockIdx.x;
    if (b < 8) {
        __shared__ float z[64];
        int k0 = b << 6;
        if (t < 64) {
            int k = k0 + t;
            float s = a1b[k];
            #pragma unroll
            for (int g = 0; g < 8; g++) s += partA[(g << 9) + k];
            z[t] = fmaxf(s, 0.f);
        }
        __syncthreads();
        float acc = 0.f;
        #pragma unroll 8
        for (int j = 0; j < 64; j++) acc = fmaf(z[j], a2w[(k0 + j) * HD + t], acc);
        if (b == 0) acc += a2b[t];
        atomicAdd(&out[t], acc);
    } else {
        __shared__ float red[128];
        float acc = 0.f;
        for (int k = t; k < LIND; k += 128) {
            float s = c1b[k];
            #pragma unroll
            for (int g = 0; g < 8; g++) s += partC[(g << 9) + k];
            acc = fmaf(fmaxf(s, 0.f), c2w[k], acc);
        }
        red[t] = acc;
        __syncthreads();
        if (t == 0) {
            float vv = c2b[0];
            for (int k = 0; k < 128; k++) vv += red[k];
            out[HD] = vv;
        }
    }
}

extern "C" void kernel_launch(void* const* d_in, const int* in_sizes, int n_in,
                              void* d_out, int out_size, void* d_ws, size_t ws_size,
                              hipStream_t stream) {
    const int*   cls  = (const int*)d_in[0];
    const float* norm = (const float*)d_in[1];
    const int*   src  = (const int*)d_in[2];
    const int*   dst  = (const int*)d_in[3];
    const float* W0   = (const float*)d_in[4];
    const float* W1   = (const float*)d_in[5];
    const float* W2   = (const float*)d_in[6];
    const float* a1w  = (const float*)d_in[7];
    const float* a1b  = (const float*)d_in[8];
    const float* a2w  = (const float*)d_in[9];
    const float* a2b  = (const float*)d_in[10];
    const float* c1w  = (const float*)d_in[11];
    const float* c1b  = (const float*)d_in[12];
    const float* c2w  = (const float*)d_in[13];
    const float* c2b  = (const float*)d_in[14];
    float* out = (float*)d_out;

    // workspace layout (bytes); total ~3.3 MB
    char* ws = (char*)d_ws;
    int*   cnt      = (int*)(ws + 0);
    int*   map1     = (int*)(ws + 32);
    int*   map0     = (int*)(ws + 200032);
    int*   list1    = (int*)(ws + 400032);
    int*   list0    = (int*)(ws + 404128);
    int*   e0_src   = (int*)(ws + 420512);
    int*   e1_src   = (int*)(ws + 436896);
    int*   e1_dslot = (int*)(ws + 567968);
    float* M0       = (float*)(ws + 699040);  // NR*HD
    float* w0sum    = (float*)(ws + 707232);  // CAP0*NR = 256 KB
    float* msg1     = (float*)(ws + 969376);  // CAP0*HD = 2 MB
    float* agg1     = (float*)(ws + 3066528); // CAP1*HD = 512 KB
    float* msg2     = (float*)(ws + 3590816); // CAP1*HD = 512 KB
    float* partA    = (float*)(ws + 4115104); // 8*512
    float* partC    = (float*)(ws + 4131488); // 8*512

    k_init<<<512, 256, 0, stream>>>(cnt, w0sum, agg1, M0, W0, out);
    k_scanA<<<1600, 256, 0, stream>>>(src, dst, map1, list1, e0_src, cnt);
    k_scanB1<<<1600, 256, 0, stream>>>(src, dst, map1, map0, list0, e1_src, e1_dslot, cnt);
    k_scanB2<<<1600, 256, 0, stream>>>(src, dst, map0, cls, norm, w0sum);
    k_msg1<<<CAP0, 128, 0, stream>>>(cnt, list0, cls, norm, w0sum, M0, W1, msg1);
    k_agg1<<<128, 256, 0, stream>>>(cnt, e1_src, e1_dslot, map0, msg1, agg1);
    k_msg<<<CAP1, 128, 0, stream>>>(cnt, C_N1, CAP1, list1, cls, norm, agg1, W2, msg2);
    k_hidden<<<16, 512, 0, stream>>>(cnt, e0_src, map1, msg2, a1w, c1w, partA, partC);
    k_out<<<9, 128, 0, stream>>>(partA, partC, a1b, a2w, a2b, c1b, c2w, c2b, out);
}